// Round 4
// baseline (86.407 us; speedup 1.0000x reference)
//
#include <hip/hip_runtime.h>

// RQCNN quanvolution: B=32, C=3, H=W=128, K=2 -> R=127, 4 qubits, 4 layers.
// Output [B,4,R,R] is a flat reinterpretation of q_out [B,R,R,4], so each
// thread writes one coalesced float4 at tid = ((b*R + i)*R + j).

#define BATCH   32
#define CHAN    3
#define HDIM    128
#define WDIM    128
#define RDIM    127
#define NLAYERS 4

__global__ __launch_bounds__(256) void rqcnn_kernel(
    const float* __restrict__ x,   // [B,C,H,W]
    const float* __restrict__ w,   // [4,4] weights
    float* __restrict__ out)       // [B*R*R*4]
{
    __shared__ float cw[16], sw[16];
    const int t = threadIdx.x;
    if (t < 16) {
        float wv = w[t];
        __sincosf(0.5f * wv, &sw[t], &cw[t]);
    }
    __syncthreads();

    const int NPIX = BATCH * RDIM * RDIM;
    int tid = blockIdx.x * 256 + t;
    if (tid >= NPIX) return;

    int j    = tid % RDIM;
    int rest = tid / RDIM;
    int i    = rest % RDIM;
    int b    = rest / RDIM;

    float z0 = 0.f, z1 = 0.f, z2 = 0.f, z3 = 0.f;

    for (int c = 0; c < CHAN; ++c) {
        int base = ((b * CHAN + c) * HDIM + i) * WDIM + j;
        float v0 = x[base];
        float v1 = x[base + 1];
        float v2 = x[base + WDIM];
        float v3 = x[base + WDIM + 1];

        // encoding: RY(pi*x) product state; amp = (cos(pi*x/2), sin(pi*x/2))
        const float hp = 1.5707963267948966f;
        float ca0, sa0, ca1, sa1, ca2, sa2, ca3, sa3;
        __sincosf(hp * v0, &sa0, &ca0);
        __sincosf(hp * v1, &sa1, &ca1);
        __sincosf(hp * v2, &sa2, &ca2);
        __sincosf(hp * v3, &sa3, &ca3);

        // qubit q maps to bit (3-q) of flat index s = a*8 + b*4 + c*2 + d
        float aq[2] = {ca0, sa0};
        float bq[2] = {ca1, sa1};
        float cq[2] = {ca2, sa2};
        float dq[2] = {ca3, sa3};

        float st[16];
        #pragma unroll
        for (int ia = 0; ia < 2; ++ia) {
            #pragma unroll
            for (int ib = 0; ib < 2; ++ib) {
                float ab = aq[ia] * bq[ib];
                #pragma unroll
                for (int ic = 0; ic < 2; ++ic) {
                    float abc = ab * cq[ic];
                    #pragma unroll
                    for (int id = 0; id < 2; ++id)
                        st[ia*8 + ib*4 + ic*2 + id] = abc * dq[id];
                }
            }
        }

        #pragma unroll
        for (int l = 0; l < NLAYERS; ++l) {
            // RY on each qubit q (bit position 3-q)
            #pragma unroll
            for (int q = 0; q < 4; ++q) {
                float cc = cw[l*4 + q];
                float ss = sw[l*4 + q];
                const int m = 1 << (3 - q);
                #pragma unroll
                for (int s0 = 0; s0 < 16; ++s0) {
                    if (s0 & m) continue;
                    int s1i = s0 | m;
                    float a0 = st[s0], a1 = st[s1i];
                    st[s0]  = cc * a0 - ss * a1;
                    st[s1i] = ss * a0 + cc * a1;
                }
            }
            // CNOT(0,1): ctrl bit3, tgt bit2
            #pragma unroll
            for (int s0 = 0; s0 < 16; ++s0)
                if ((s0 & 8) && !(s0 & 4)) { float tmp = st[s0]; st[s0] = st[s0|4]; st[s0|4] = tmp; }
            // CNOT(2,3): ctrl bit1, tgt bit0
            #pragma unroll
            for (int s0 = 0; s0 < 16; ++s0)
                if ((s0 & 2) && !(s0 & 1)) { float tmp = st[s0]; st[s0] = st[s0|1]; st[s0|1] = tmp; }
            // CNOT(1,2): ctrl bit2, tgt bit1
            #pragma unroll
            for (int s0 = 0; s0 < 16; ++s0)
                if ((s0 & 4) && !(s0 & 2)) { float tmp = st[s0]; st[s0] = st[s0|2]; st[s0|2] = tmp; }
        }

        // <Z_q> = sum_s (+/-) st[s]^2, sign by bit (3-q)
        #pragma unroll
        for (int s0 = 0; s0 < 16; ++s0) {
            float p = st[s0] * st[s0];
            z0 += (s0 & 8) ? -p : p;
            z1 += (s0 & 4) ? -p : p;
            z2 += (s0 & 2) ? -p : p;
            z3 += (s0 & 1) ? -p : p;
        }
    }

    reinterpret_cast<float4*>(out)[tid] = make_float4(z0, z1, z2, z3);
}

extern "C" void kernel_launch(void* const* d_in, const int* in_sizes, int n_in,
                              void* d_out, int out_size, void* d_ws, size_t ws_size,
                              hipStream_t stream) {
    const float* x = (const float*)d_in[0];
    const float* w = (const float*)d_in[1];
    float* out = (float*)d_out;

    const int NPIX = BATCH * RDIM * RDIM;           // 516,128
    int blocks = (NPIX + 255) / 256;                // 2017
    rqcnn_kernel<<<blocks, 256, 0, stream>>>(x, w, out);
}

// Round 5
// 78.894 us; speedup vs baseline: 1.0952x; 1.0952x over previous
//
#include <hip/hip_runtime.h>

// RQCNN quanvolution: B=32, C=3, H=W=128, K=2 -> R=127, 4 qubits, 4 layers.
// Output [B,4,R,R] is a flat reinterpretation of q_out [B,R,R,4], so each
// thread writes one coalesced float4 at tid = ((b*R + i)*R + j).
//
// R5 changes vs R4 baseline (86.4 us):
//  - __sincosf -> raw v_sin_f32/v_cos_f32 (__builtin_amdgcn_{sin,cos}f).
//    Inputs are in REVOLUTIONS: sin(pi*v/2) = v_sin(v*0.25). Args are all in
//    [0,0.5) so no range reduction is ever needed -> 1 mul + 1 trans op.
//  - weight cos/sin hoisted LDS->registers once per thread (kills in-loop
//    ds_read + lgkmcnt waits; indices all compile-time -> VGPRs).
//  - Z-expectation sums factorized via 4+4 partial sums (80 -> ~52 instr).

#define BATCH   32
#define CHAN    3
#define HDIM    128
#define WDIM    128
#define RDIM    127
#define NLAYERS 4

__global__ __launch_bounds__(256) void rqcnn_kernel(
    const float* __restrict__ x,   // [B,C,H,W]
    const float* __restrict__ w,   // [4,4] weights
    float* __restrict__ out)       // [B*R*R*4]
{
    __shared__ float cw_s[16], sw_s[16];
    const int t = threadIdx.x;
    if (t < 16) {
        // cos(w/2), sin(w/2); w in [0,2pi) -> revolutions arg = w/(4pi) in [0,0.5)
        float rev = w[t] * 0.07957747154594767f;  // 1/(4*pi)
        cw_s[t] = __builtin_amdgcn_cosf(rev);
        sw_s[t] = __builtin_amdgcn_sinf(rev);
    }
    __syncthreads();

    // hoist weights to registers (compile-time indices -> VGPRs, one-time LDS read)
    float cw[16], sw[16];
    #pragma unroll
    for (int k = 0; k < 16; ++k) { cw[k] = cw_s[k]; sw[k] = sw_s[k]; }

    const int NPIX = BATCH * RDIM * RDIM;
    int tid = blockIdx.x * 256 + t;
    if (tid >= NPIX) return;

    int j    = tid % RDIM;
    int rest = tid / RDIM;
    int i    = rest % RDIM;
    int b    = rest / RDIM;

    float z0 = 0.f, z1 = 0.f, z2 = 0.f, z3 = 0.f;

    for (int c = 0; c < CHAN; ++c) {
        int base = ((b * CHAN + c) * HDIM + i) * WDIM + j;
        float v0 = x[base];
        float v1 = x[base + 1];
        float v2 = x[base + WDIM];
        float v3 = x[base + WDIM + 1];

        // encoding: RY(pi*x) product state; amp = (cos(pi*x/2), sin(pi*x/2))
        // v_sin/v_cos take revolutions: pi*v/2 radians = v/4 revolutions.
        float ca0 = __builtin_amdgcn_cosf(0.25f * v0), sa0 = __builtin_amdgcn_sinf(0.25f * v0);
        float ca1 = __builtin_amdgcn_cosf(0.25f * v1), sa1 = __builtin_amdgcn_sinf(0.25f * v1);
        float ca2 = __builtin_amdgcn_cosf(0.25f * v2), sa2 = __builtin_amdgcn_sinf(0.25f * v2);
        float ca3 = __builtin_amdgcn_cosf(0.25f * v3), sa3 = __builtin_amdgcn_sinf(0.25f * v3);

        // qubit q maps to bit (3-q) of flat index s = a*8 + b*4 + c*2 + d
        float aq[2] = {ca0, sa0};
        float bq[2] = {ca1, sa1};
        float cq[2] = {ca2, sa2};
        float dq[2] = {ca3, sa3};

        float st[16];
        #pragma unroll
        for (int ia = 0; ia < 2; ++ia) {
            #pragma unroll
            for (int ib = 0; ib < 2; ++ib) {
                float ab = aq[ia] * bq[ib];
                #pragma unroll
                for (int ic = 0; ic < 2; ++ic) {
                    float abc = ab * cq[ic];
                    #pragma unroll
                    for (int id = 0; id < 2; ++id)
                        st[ia*8 + ib*4 + ic*2 + id] = abc * dq[id];
                }
            }
        }

        #pragma unroll
        for (int l = 0; l < NLAYERS; ++l) {
            // RY on each qubit q (bit position 3-q)
            #pragma unroll
            for (int q = 0; q < 4; ++q) {
                float cc = cw[l*4 + q];
                float ss = sw[l*4 + q];
                const int m = 1 << (3 - q);
                #pragma unroll
                for (int s0 = 0; s0 < 16; ++s0) {
                    if (s0 & m) continue;
                    int s1i = s0 | m;
                    float a0 = st[s0], a1 = st[s1i];
                    st[s0]  = cc * a0 - ss * a1;
                    st[s1i] = ss * a0 + cc * a1;
                }
            }
            // CNOT(0,1): ctrl bit3, tgt bit2
            #pragma unroll
            for (int s0 = 0; s0 < 16; ++s0)
                if ((s0 & 8) && !(s0 & 4)) { float tmp = st[s0]; st[s0] = st[s0|4]; st[s0|4] = tmp; }
            // CNOT(2,3): ctrl bit1, tgt bit0
            #pragma unroll
            for (int s0 = 0; s0 < 16; ++s0)
                if ((s0 & 2) && !(s0 & 1)) { float tmp = st[s0]; st[s0] = st[s0|1]; st[s0|1] = tmp; }
            // CNOT(1,2): ctrl bit2, tgt bit1
            #pragma unroll
            for (int s0 = 0; s0 < 16; ++s0)
                if ((s0 & 4) && !(s0 & 2)) { float tmp = st[s0]; st[s0] = st[s0|2]; st[s0|2] = tmp; }
        }

        // probabilities
        float p[16];
        #pragma unroll
        for (int s0 = 0; s0 < 16; ++s0) p[s0] = st[s0] * st[s0];

        // A[i] = sum over low 2 bits (i = bits a,b); B[j] = sum over high 2 bits (j = bits c,d)
        float A0 = (p[0] + p[1]) + (p[2] + p[3]);
        float A1 = (p[4] + p[5]) + (p[6] + p[7]);
        float A2 = (p[8] + p[9]) + (p[10] + p[11]);
        float A3 = (p[12] + p[13]) + (p[14] + p[15]);
        float B0 = (p[0] + p[4]) + (p[8] + p[12]);
        float B1 = (p[1] + p[5]) + (p[9] + p[13]);
        float B2 = (p[2] + p[6]) + (p[10] + p[14]);
        float B3 = (p[3] + p[7]) + (p[11] + p[15]);
        z0 += (A0 + A1) - (A2 + A3);   // sign by bit3 (a)
        z1 += (A0 + A2) - (A1 + A3);   // sign by bit2 (b)
        z2 += (B0 + B1) - (B2 + B3);   // sign by bit1 (c)
        z3 += (B0 + B2) - (B1 + B3);   // sign by bit0 (d)
    }

    reinterpret_cast<float4*>(out)[tid] = make_float4(z0, z1, z2, z3);
}

extern "C" void kernel_launch(void* const* d_in, const int* in_sizes, int n_in,
                              void* d_out, int out_size, void* d_ws, size_t ws_size,
                              hipStream_t stream) {
    const float* x = (const float*)d_in[0];
    const float* w = (const float*)d_in[1];
    float* out = (float*)d_out;

    const int NPIX = BATCH * RDIM * RDIM;           // 516,128
    int blocks = (NPIX + 255) / 256;                // 2017
    rqcnn_kernel<<<blocks, 256, 0, stream>>>(x, w, out);
}

// Round 6
// 70.828 us; speedup vs baseline: 1.2200x; 1.1139x over previous
//
#include <hip/hip_runtime.h>

// RQCNN quanvolution: B=32, C=3, H=W=128, K=2 -> R=127, 4 qubits, 4 layers.
// Output [B,4,R,R] is a flat reinterpretation of q_out [B,R,R,4].
//
// R6 changes vs R5 (78.9 us):
//  - Layer-0 RY merged into encoding: RY(w)RY(pi*x)=RY(pi*x+w) -> first RY
//    layer is free (angle add), deletes 128 FMA/channel.
//  - 2 pixels per thread (b and b+16) with ALL circuit state as float2
//    ext-vectors -> backend can emit v_pk_fma_f32/v_pk_mul_f32 (2x f32 rate).
//    32 = 2*16 so there is no tail; output = two coalesced float4 stores.

#define BATCH   32
#define CHAN    3
#define HDIM    128
#define WDIM    128
#define RDIM    127
#define HALFB   16

typedef float v2 __attribute__((ext_vector_type(2)));

__global__ __launch_bounds__(256) void rqcnn_kernel(
    const float* __restrict__ x,   // [B,C,H,W]
    const float* __restrict__ w,   // [4,4] weights
    float* __restrict__ out)       // [B*R*R*4]
{
    __shared__ float cw_s[16], sw_s[16], wrev_s[4];
    const int t = threadIdx.x;
    if (t < 16) {
        // layers 1..3 need cos(w/2), sin(w/2); rev arg = w/(4*pi)
        float rev = w[t] * 0.07957747154594767f;  // 1/(4*pi)
        cw_s[t] = __builtin_amdgcn_cosf(rev);
        sw_s[t] = __builtin_amdgcn_sinf(rev);
        if (t < 4) wrev_s[t] = rev;               // layer-0 weights, merged into encoding
    }
    __syncthreads();

    // hoist to registers (compile-time indices -> VGPRs, one-time LDS read)
    float cw[12], sw[12];
    #pragma unroll
    for (int k = 0; k < 12; ++k) { cw[k] = cw_s[k + 4]; sw[k] = sw_s[k + 4]; }
    float wr0 = wrev_s[0], wr1 = wrev_s[1], wr2 = wrev_s[2], wr3 = wrev_s[3];

    const int NHALF = HALFB * RDIM * RDIM;     // 258,064 threads, 2 pixels each
    int tid = blockIdx.x * 256 + t;
    if (tid >= NHALF) return;

    int j    = tid % RDIM;
    int rest = tid / RDIM;
    int i    = rest % RDIM;
    int b    = rest / RDIM;                    // 0..15; second pixel is b+16

    const int XOFF = HALFB * CHAN * HDIM * WDIM;   // offset of batch b+16

    v2 z0 = 0.f, z1 = 0.f, z2 = 0.f, z3 = 0.f;

    for (int c = 0; c < CHAN; ++c) {
        int base = ((b * CHAN + c) * HDIM + i) * WDIM + j;
        v2 v0, v1, v2v, v3;
        v0.x  = x[base];              v0.y  = x[base + XOFF];
        v1.x  = x[base + 1];          v1.y  = x[base + XOFF + 1];
        v2v.x = x[base + WDIM];       v2v.y = x[base + XOFF + WDIM];
        v3.x  = x[base + WDIM + 1];   v3.y  = x[base + XOFF + WDIM + 1];

        // merged encoding + layer-0 RY: half-angle (pi*v + w0q)/2
        // revolutions: v/4 + w0q/(4*pi)
        v2 a0 = 0.25f * v0 + wr0;
        v2 a1 = 0.25f * v1 + wr1;
        v2 a2 = 0.25f * v2v + wr2;
        v2 a3 = 0.25f * v3 + wr3;

        v2 ca0, sa0, ca1, sa1, ca2, sa2, ca3, sa3;
        ca0.x = __builtin_amdgcn_cosf(a0.x); ca0.y = __builtin_amdgcn_cosf(a0.y);
        sa0.x = __builtin_amdgcn_sinf(a0.x); sa0.y = __builtin_amdgcn_sinf(a0.y);
        ca1.x = __builtin_amdgcn_cosf(a1.x); ca1.y = __builtin_amdgcn_cosf(a1.y);
        sa1.x = __builtin_amdgcn_sinf(a1.x); sa1.y = __builtin_amdgcn_sinf(a1.y);
        ca2.x = __builtin_amdgcn_cosf(a2.x); ca2.y = __builtin_amdgcn_cosf(a2.y);
        sa2.x = __builtin_amdgcn_sinf(a2.x); sa2.y = __builtin_amdgcn_sinf(a2.y);
        ca3.x = __builtin_amdgcn_cosf(a3.x); ca3.y = __builtin_amdgcn_cosf(a3.y);
        sa3.x = __builtin_amdgcn_sinf(a3.x); sa3.y = __builtin_amdgcn_sinf(a3.y);

        // qubit q maps to bit (3-q) of flat index s
        v2 aq[2] = {ca0, sa0};
        v2 bq[2] = {ca1, sa1};
        v2 cq[2] = {ca2, sa2};
        v2 dq[2] = {ca3, sa3};

        v2 st[16];
        #pragma unroll
        for (int ia = 0; ia < 2; ++ia) {
            #pragma unroll
            for (int ib = 0; ib < 2; ++ib) {
                v2 ab = aq[ia] * bq[ib];
                #pragma unroll
                for (int ic = 0; ic < 2; ++ic) {
                    v2 abc = ab * cq[ic];
                    #pragma unroll
                    for (int id = 0; id < 2; ++id)
                        st[ia*8 + ib*4 + ic*2 + id] = abc * dq[id];
                }
            }
        }

        // layer-0 CNOTs (RYs already merged): CNOT(0,1), CNOT(2,3), CNOT(1,2)
        #pragma unroll
        for (int s0 = 0; s0 < 16; ++s0)
            if ((s0 & 8) && !(s0 & 4)) { v2 tmp = st[s0]; st[s0] = st[s0|4]; st[s0|4] = tmp; }
        #pragma unroll
        for (int s0 = 0; s0 < 16; ++s0)
            if ((s0 & 2) && !(s0 & 1)) { v2 tmp = st[s0]; st[s0] = st[s0|1]; st[s0|1] = tmp; }
        #pragma unroll
        for (int s0 = 0; s0 < 16; ++s0)
            if ((s0 & 4) && !(s0 & 2)) { v2 tmp = st[s0]; st[s0] = st[s0|2]; st[s0|2] = tmp; }

        // layers 1..3: RY on all 4 qubits, then the 3 CNOTs
        #pragma unroll
        for (int l = 0; l < 3; ++l) {
            #pragma unroll
            for (int q = 0; q < 4; ++q) {
                float cc = cw[l*4 + q];
                float ss = sw[l*4 + q];
                const int m = 1 << (3 - q);
                #pragma unroll
                for (int s0 = 0; s0 < 16; ++s0) {
                    if (s0 & m) continue;
                    int s1i = s0 | m;
                    v2 va = st[s0], vb = st[s1i];
                    st[s0]  = cc * va - ss * vb;
                    st[s1i] = ss * va + cc * vb;
                }
            }
            #pragma unroll
            for (int s0 = 0; s0 < 16; ++s0)
                if ((s0 & 8) && !(s0 & 4)) { v2 tmp = st[s0]; st[s0] = st[s0|4]; st[s0|4] = tmp; }
            #pragma unroll
            for (int s0 = 0; s0 < 16; ++s0)
                if ((s0 & 2) && !(s0 & 1)) { v2 tmp = st[s0]; st[s0] = st[s0|1]; st[s0|1] = tmp; }
            #pragma unroll
            for (int s0 = 0; s0 < 16; ++s0)
                if ((s0 & 4) && !(s0 & 2)) { v2 tmp = st[s0]; st[s0] = st[s0|2]; st[s0|2] = tmp; }
        }

        // probabilities + factorized signed sums
        v2 p[16];
        #pragma unroll
        for (int s0 = 0; s0 < 16; ++s0) p[s0] = st[s0] * st[s0];

        v2 A0 = (p[0] + p[1]) + (p[2] + p[3]);
        v2 A1 = (p[4] + p[5]) + (p[6] + p[7]);
        v2 A2 = (p[8] + p[9]) + (p[10] + p[11]);
        v2 A3 = (p[12] + p[13]) + (p[14] + p[15]);
        v2 B0 = (p[0] + p[4]) + (p[8] + p[12]);
        v2 B1 = (p[1] + p[5]) + (p[9] + p[13]);
        v2 B2 = (p[2] + p[6]) + (p[10] + p[14]);
        v2 B3 = (p[3] + p[7]) + (p[11] + p[15]);
        z0 += (A0 + A1) - (A2 + A3);   // sign by bit3
        z1 += (A0 + A2) - (A1 + A3);   // sign by bit2
        z2 += (B0 + B1) - (B2 + B3);   // sign by bit1
        z3 += (B0 + B2) - (B1 + B3);   // sign by bit0
    }

    // pixel 1 at tid, pixel 2 at tid + 16*127*127
    reinterpret_cast<float4*>(out)[tid]         = make_float4(z0.x, z1.x, z2.x, z3.x);
    reinterpret_cast<float4*>(out)[tid + NHALF] = make_float4(z0.y, z1.y, z2.y, z3.y);
}

extern "C" void kernel_launch(void* const* d_in, const int* in_sizes, int n_in,
                              void* d_out, int out_size, void* d_ws, size_t ws_size,
                              hipStream_t stream) {
    const float* x = (const float*)d_in[0];
    const float* w = (const float*)d_in[1];
    float* out = (float*)d_out;

    const int NHALF = HALFB * RDIM * RDIM;          // 258,064
    int blocks = (NHALF + 255) / 256;               // 1009
    rqcnn_kernel<<<blocks, 256, 0, stream>>>(x, w, out);
}

// Round 7
// 67.099 us; speedup vs baseline: 1.2878x; 1.0556x over previous
//
#include <hip/hip_runtime.h>

// RQCNN quanvolution: B=32, C=3, H=W=128, K=2 -> R=127, 4 qubits, 4 layers.
// Output [B,4,R,R] is a flat reinterpretation of q_out [B,R,R,4].
//
// R7 changes vs R6 (70.8 us):
//  - tan-Givens: RY(w) = cos(w/2) * [[1,-t],[t,1]], t = tan(w/2). The cos
//    scale is uniform over the state and commutes with CNOT permutations, so
//    S = prod cos(w_lq/2) over layers 1..3 folds into one S^2 multiply of z
//    after the channel loop. Rotation pair: 4 instr -> 2 FMA (384 -> 192
//    v2-instr/channel).
//  - Layer-0 RY stays merged into the encoding angles (R6).

#define BATCH   32
#define CHAN    3
#define HDIM    128
#define WDIM    128
#define RDIM    127
#define HALFB   16

typedef float v2 __attribute__((ext_vector_type(2)));

__global__ __launch_bounds__(256) void rqcnn_kernel(
    const float* __restrict__ x,   // [B,C,H,W]
    const float* __restrict__ w,   // [4,4] weights
    float* __restrict__ out)       // [B*R*R*4]
{
    __shared__ float tw_s[12];     // tan(w/2) for layers 1..3
    __shared__ float wrev_s[4];    // layer-0 weights in revolutions (merged into encoding)
    __shared__ float cw_tmp[16];
    __shared__ float sc2_s;        // (prod cos(w/2), layers 1..3)^2
    const int t = threadIdx.x;
    if (t < 16) {
        float rev = w[t] * 0.07957747154594767f;   // w/(4*pi): half-angle in revolutions
        float c = __builtin_amdgcn_cosf(rev);
        float s = __builtin_amdgcn_sinf(rev);
        cw_tmp[t] = c;
        if (t >= 4) tw_s[t - 4] = s / c;           // precise div, once per block
        else        wrev_s[t]   = rev;
    }
    __syncthreads();
    if (t == 0) {
        float P = 1.f;
        #pragma unroll
        for (int k = 4; k < 16; ++k) P *= cw_tmp[k];
        sc2_s = P * P;
    }
    __syncthreads();

    // hoist to registers (compile-time indices -> VGPRs, one-time LDS read)
    float tw[12];
    #pragma unroll
    for (int k = 0; k < 12; ++k) tw[k] = tw_s[k];
    float wr0 = wrev_s[0], wr1 = wrev_s[1], wr2 = wrev_s[2], wr3 = wrev_s[3];
    float sc2 = sc2_s;

    const int NHALF = HALFB * RDIM * RDIM;     // 258,064 threads, 2 pixels each
    int tid = blockIdx.x * 256 + t;
    if (tid >= NHALF) return;

    int j    = tid % RDIM;
    int rest = tid / RDIM;
    int i    = rest % RDIM;
    int b    = rest / RDIM;                    // 0..15; second pixel is b+16

    const int XOFF = HALFB * CHAN * HDIM * WDIM;   // offset of batch b+16

    v2 z0 = 0.f, z1 = 0.f, z2 = 0.f, z3 = 0.f;

    for (int c = 0; c < CHAN; ++c) {
        int base = ((b * CHAN + c) * HDIM + i) * WDIM + j;
        v2 v0, v1, v2v, v3;
        v0.x  = x[base];              v0.y  = x[base + XOFF];
        v1.x  = x[base + 1];          v1.y  = x[base + XOFF + 1];
        v2v.x = x[base + WDIM];       v2v.y = x[base + XOFF + WDIM];
        v3.x  = x[base + WDIM + 1];   v3.y  = x[base + XOFF + WDIM + 1];

        // merged encoding + layer-0 RY: half-angle (pi*v + w0q)/2 in revolutions
        v2 a0 = 0.25f * v0 + wr0;
        v2 a1 = 0.25f * v1 + wr1;
        v2 a2 = 0.25f * v2v + wr2;
        v2 a3 = 0.25f * v3 + wr3;

        v2 ca0, sa0, ca1, sa1, ca2, sa2, ca3, sa3;
        ca0.x = __builtin_amdgcn_cosf(a0.x); ca0.y = __builtin_amdgcn_cosf(a0.y);
        sa0.x = __builtin_amdgcn_sinf(a0.x); sa0.y = __builtin_amdgcn_sinf(a0.y);
        ca1.x = __builtin_amdgcn_cosf(a1.x); ca1.y = __builtin_amdgcn_cosf(a1.y);
        sa1.x = __builtin_amdgcn_sinf(a1.x); sa1.y = __builtin_amdgcn_sinf(a1.y);
        ca2.x = __builtin_amdgcn_cosf(a2.x); ca2.y = __builtin_amdgcn_cosf(a2.y);
        sa2.x = __builtin_amdgcn_sinf(a2.x); sa2.y = __builtin_amdgcn_sinf(a2.y);
        ca3.x = __builtin_amdgcn_cosf(a3.x); ca3.y = __builtin_amdgcn_cosf(a3.y);
        sa3.x = __builtin_amdgcn_sinf(a3.x); sa3.y = __builtin_amdgcn_sinf(a3.y);

        // qubit q maps to bit (3-q) of flat index s
        v2 aq[2] = {ca0, sa0};
        v2 bq[2] = {ca1, sa1};
        v2 cq[2] = {ca2, sa2};
        v2 dq[2] = {ca3, sa3};

        v2 st[16];
        #pragma unroll
        for (int ia = 0; ia < 2; ++ia) {
            #pragma unroll
            for (int ib = 0; ib < 2; ++ib) {
                v2 ab = aq[ia] * bq[ib];
                #pragma unroll
                for (int ic = 0; ic < 2; ++ic) {
                    v2 abc = ab * cq[ic];
                    #pragma unroll
                    for (int id = 0; id < 2; ++id)
                        st[ia*8 + ib*4 + ic*2 + id] = abc * dq[id];
                }
            }
        }

        // layer-0 CNOTs (RYs merged): CNOT(0,1), CNOT(2,3), CNOT(1,2)
        #pragma unroll
        for (int s0 = 0; s0 < 16; ++s0)
            if ((s0 & 8) && !(s0 & 4)) { v2 tmp = st[s0]; st[s0] = st[s0|4]; st[s0|4] = tmp; }
        #pragma unroll
        for (int s0 = 0; s0 < 16; ++s0)
            if ((s0 & 2) && !(s0 & 1)) { v2 tmp = st[s0]; st[s0] = st[s0|1]; st[s0|1] = tmp; }
        #pragma unroll
        for (int s0 = 0; s0 < 16; ++s0)
            if ((s0 & 4) && !(s0 & 2)) { v2 tmp = st[s0]; st[s0] = st[s0|2]; st[s0|2] = tmp; }

        // layers 1..3: tan-Givens RY (2 FMA/pair), then the 3 CNOTs
        #pragma unroll
        for (int l = 0; l < 3; ++l) {
            #pragma unroll
            for (int q = 0; q < 4; ++q) {
                float tt = tw[l*4 + q];
                const int m = 1 << (3 - q);
                #pragma unroll
                for (int s0 = 0; s0 < 16; ++s0) {
                    if (s0 & m) continue;
                    int s1i = s0 | m;
                    v2 va = st[s0], vb = st[s1i];
                    st[s0]  = va - tt * vb;   // fma
                    st[s1i] = tt * va + vb;   // fma
                }
            }
            #pragma unroll
            for (int s0 = 0; s0 < 16; ++s0)
                if ((s0 & 8) && !(s0 & 4)) { v2 tmp = st[s0]; st[s0] = st[s0|4]; st[s0|4] = tmp; }
            #pragma unroll
            for (int s0 = 0; s0 < 16; ++s0)
                if ((s0 & 2) && !(s0 & 1)) { v2 tmp = st[s0]; st[s0] = st[s0|1]; st[s0|1] = tmp; }
            #pragma unroll
            for (int s0 = 0; s0 < 16; ++s0)
                if ((s0 & 4) && !(s0 & 2)) { v2 tmp = st[s0]; st[s0] = st[s0|2]; st[s0|2] = tmp; }
        }

        // probabilities + factorized signed sums (scale folded in after c-loop)
        v2 p[16];
        #pragma unroll
        for (int s0 = 0; s0 < 16; ++s0) p[s0] = st[s0] * st[s0];

        v2 A0 = (p[0] + p[1]) + (p[2] + p[3]);
        v2 A1 = (p[4] + p[5]) + (p[6] + p[7]);
        v2 A2 = (p[8] + p[9]) + (p[10] + p[11]);
        v2 A3 = (p[12] + p[13]) + (p[14] + p[15]);
        v2 B0 = (p[0] + p[4]) + (p[8] + p[12]);
        v2 B1 = (p[1] + p[5]) + (p[9] + p[13]);
        v2 B2 = (p[2] + p[6]) + (p[10] + p[14]);
        v2 B3 = (p[3] + p[7]) + (p[11] + p[15]);
        z0 += (A0 + A1) - (A2 + A3);   // sign by bit3
        z1 += (A0 + A2) - (A1 + A3);   // sign by bit2
        z2 += (B0 + B1) - (B2 + B3);   // sign by bit1
        z3 += (B0 + B2) - (B1 + B3);   // sign by bit0
    }

    // fold the uniform tan-Givens scale (weights-only, channel-independent)
    z0 *= sc2; z1 *= sc2; z2 *= sc2; z3 *= sc2;

    // pixel 1 at tid, pixel 2 at tid + 16*127*127
    reinterpret_cast<float4*>(out)[tid]         = make_float4(z0.x, z1.x, z2.x, z3.x);
    reinterpret_cast<float4*>(out)[tid + NHALF] = make_float4(z0.y, z1.y, z2.y, z3.y);
}

extern "C" void kernel_launch(void* const* d_in, const int* in_sizes, int n_in,
                              void* d_out, int out_size, void* d_ws, size_t ws_size,
                              hipStream_t stream) {
    const float* x = (const float*)d_in[0];
    const float* w = (const float*)d_in[1];
    float* out = (float*)d_out;

    const int NHALF = HALFB * RDIM * RDIM;          // 258,064
    int blocks = (NHALF + 255) / 256;               // 1009
    rqcnn_kernel<<<blocks, 256, 0, stream>>>(x, w, out);
}